// Round 7
// baseline (1516.794 us; speedup 1.0000x reference)
//
#include <hip/hip_runtime.h>

#define EPS 1e-6f

typedef __attribute__((ext_vector_type(8))) short bf16x8;
typedef __attribute__((ext_vector_type(4))) float f32x4;
typedef __attribute__((ext_vector_type(8))) unsigned short ushort8;

#define AS1(p) ((const __attribute__((address_space(1))) void*)(p))
#define AS3(p) ((__attribute__((address_space(3))) void*)(p))

__device__ inline unsigned int fkey(float f) {
  unsigned int u = __float_as_uint(f);
  return (u & 0x80000000u) ? ~u : (u | 0x80000000u);
}

__device__ inline unsigned long long shfl_xor_u64(unsigned long long v, int mask) {
  unsigned int lo = (unsigned int)(v & 0xffffffffull);
  unsigned int hi = (unsigned int)(v >> 32);
  lo = (unsigned int)__shfl_xor((int)lo, mask);
  hi = (unsigned int)__shfl_xor((int)hi, mask);
  return (((unsigned long long)hi) << 32) | lo;
}

__device__ inline unsigned short f2bf(float f) {  // RNE fp32 -> bf16
  unsigned int u = __float_as_uint(f);
  u += 0x7fffu + ((u >> 16) & 1u);
  return (unsigned short)(u >> 16);
}
__device__ inline float bf2f(unsigned short h) {
  return __uint_as_float(((unsigned int)h) << 16);
}

// LDS byte-offset of a __shared__ address (AS3 pointers are 32-bit)
__device__ inline unsigned lds_off(const void* p) {
  return (unsigned)(unsigned long long)(__attribute__((address_space(3))) const void*)p;
}

// asm ds_read_b128 with immediate offset: compiler-untracked (we control lgkmcnt)
template<int OFF>
__device__ inline bf16x8 ds_read128(unsigned addr) {
  bf16x8 r;
  asm volatile("ds_read_b128 %0, %1 offset:%2" : "=v"(r) : "v"(addr), "i"(OFF));
  return r;
}

// asm global f32 load with immediate offset (keeps compiler vmcnt accounting clean)
template<int OFF>
__device__ inline float gload_f32(unsigned long long a) {
  float r;
  asm volatile("global_load_dword %0, %1, off offset:%2" : "=v"(r) : "v"(a), "i"(OFF));
  return r;
}

// ---------------- prep: splits + codebook norms + loss zero (one kernel) ----------------
__global__ __launch_bounds__(256) void prep_kernel(
    const float* __restrict__ x, const float* __restrict__ cbs,
    unsigned short* __restrict__ Rhi, unsigned short* __restrict__ Rlo,
    unsigned short* __restrict__ CBhi, unsigned short* __restrict__ CBlo,
    float* __restrict__ cbsq, float* __restrict__ loss_out) {
  constexpr size_t M = 32768, D = 512, C = 1024, Q = 8;
  const size_t nthreads = (size_t)gridDim.x * 256;
  const size_t gtid = (size_t)blockIdx.x * 256 + threadIdx.x;
  const int lane = threadIdx.x & 63;
  const int w = threadIdx.x >> 6;

  for (size_t i = gtid; i < M * D / 8; i += nthreads) {
    size_t off = i * 8;
    float4 v0 = *(const float4*)(x + off);
    float4 v1 = *(const float4*)(x + off + 4);
    float v[8] = {v0.x, v0.y, v0.z, v0.w, v1.x, v1.y, v1.z, v1.w};
    ushort8 h, l;
    #pragma unroll
    for (int j = 0; j < 8; j++) {
      unsigned short hh = f2bf(v[j]);
      h[j] = hh;
      l[j] = f2bf(v[j] - bf2f(hh));
    }
    *(ushort8*)(Rhi + off) = h;
    *(ushort8*)(Rlo + off) = l;
  }
  for (size_t i = gtid; i < Q * C * D / 8; i += nthreads) {
    size_t off = i * 8;
    float4 v0 = *(const float4*)(cbs + off);
    float4 v1 = *(const float4*)(cbs + off + 4);
    float v[8] = {v0.x, v0.y, v0.z, v0.w, v1.x, v1.y, v1.z, v1.w};
    ushort8 h, l;
    #pragma unroll
    for (int j = 0; j < 8; j++) {
      unsigned short hh = f2bf(v[j]);
      h[j] = hh;
      l[j] = f2bf(v[j] - bf2f(hh));
    }
    *(ushort8*)(CBhi + off) = h;
    *(ushort8*)(CBlo + off) = l;
  }
  for (int row = blockIdx.x * 4 + w; row < (int)(Q * C); row += gridDim.x * 4) {
    const float4* p = (const float4*)(cbs + (size_t)row * 512);
    float4 v0 = p[lane];
    float4 v1 = p[lane + 64];
    float s = v0.x*v0.x + v0.y*v0.y + v0.z*v0.z + v0.w*v0.w
            + v1.x*v1.x + v1.y*v1.y + v1.z*v1.z + v1.w*v1.w;
    #pragma unroll
    for (int off = 32; off; off >>= 1) s += __shfl_xor(s, off);
    if (lane == 0) cbsq[row] = s;
  }
  if (blockIdx.x == 0 && threadIdx.x < (int)Q) loss_out[threadIdx.x] = 0.f;
}

// ---------------- fused stage: 2-blocks/CU pipelined MFMA argmin + rotate ----------------
// Grid 512 x 256 threads (2 blocks/CU, 4 waves each -- cross-block TLP hides the
// barrier/wait stalls that capped every 1-block/CU schedule at ~150us). Block owns
// 64 rows; 64 K-steps (4 col-tiles x 16 BK=32). Wave grid 1x4, wave tile 64x64
// (acc 4x4) -- per-wave geometry identical to R3/R6. 2 LDS buffers, 81920 B EXACTLY
// (2x[A 8KB + B 32KB]; argmin/loss scratch overlaid into the A region post-loop).
// Per iter: 15 read-ahead ds_reads(t+1) -> lazy lgkmcnt(15) (retires frags(t), a
// full iteration of pipe time) -> barrier#1 -> stage(t+2) into the just-retired
// buffer -> 48 MFMA -> vmcnt(0) (stage ~2000cy old > HBM latency) -> barrier#2.
// Buffer parity is compile-time (macro literals) -> all LDS addrs are immediates.
__global__ __launch_bounds__(256, 2) void stage_kernel(
    const float* __restrict__ x, const float* __restrict__ cbq_f32,
    unsigned short* __restrict__ Rhi, unsigned short* __restrict__ Rlo,
    const unsigned short* __restrict__ Chi, const unsigned short* __restrict__ Clo,
    const float* __restrict__ cq_base, float* __restrict__ qout,
    float* __restrict__ idx_out, float* __restrict__ loss_out,
    int qi, int last) {
  // SM layout (ushort elems): A buf b at b*4096 ([hi 2048][lo 2048]);
  // B buf b at 8192 + b*16384 ([hi 8192][lo 8192]). Total 40960 elems = 81920 B.
  __shared__ unsigned short SM[40960];

  const int tid = threadIdx.x;
  const int lane = tid & 63;
  const int w = tid >> 6;              // 0..3
  const int wc = w;                    // wave col group (wave tile 64x64)
  const int row0 = blockIdx.x * 64;

  // staging: lane -> (row-in-chunk rw, LDS slot oq); global octet pre-swizzled
  const int rw = lane >> 2, oq = lane & 3;
  const int o_sw = (oq - rw - (rw >> 2)) & 3;
  // fragment read: lane -> (row m, k-octet g); swizzled slot
  const int m = lane & 15, g = lane >> 4;
  const int f_sw8 = ((g + m + (m >> 2)) & 3) * 8;

  // global staging base pointers (per-lane)
  const unsigned short* pAhi = Rhi + (size_t)(row0 + w * 16 + rw) * 512 + o_sw * 8;
  const unsigned short* pAlo = Rlo + (size_t)(row0 + w * 16 + rw) * 512 + o_sw * 8;
  const unsigned short* pBhi = Chi + (size_t)(w * 64 + rw) * 512 + o_sw * 8;
  const unsigned short* pBlo = Clo + (size_t)(w * 64 + rw) * 512 + o_sw * 8;

  // LDS read base addresses (bytes); buffer select via immediate offsets
  const unsigned aA = lds_off(&SM[m * 32 + f_sw8]);
  const unsigned aB = lds_off(&SM[8192 + (wc * 64 + m) * 32 + f_sw8]);

  unsigned long long best[4][4];
  #pragma unroll
  for (int mi = 0; mi < 4; mi++)
    #pragma unroll
    for (int r = 0; r < 4; r++) best[mi][r] = ~0ull;

  // stage K-step t into buffer buf: 10 global_load_lds per wave (A hi/lo + 4x B hi/lo)
  auto stage = [&](int buf, int t) {
    const size_t ko = (size_t)((t & 15) * 32);
    const size_t cof = (size_t)((t >> 4) * 256) * 512;
    unsigned short* dAh = &SM[buf * 4096 + w * 512];
    unsigned short* dAl = dAh + 2048;
    unsigned short* dBh = &SM[8192 + buf * 16384 + w * 2048];
    unsigned short* dBl = dBh + 8192;
    __builtin_amdgcn_global_load_lds(AS1(pAhi + ko), AS3(dAh), 16, 0, 0);
    __builtin_amdgcn_global_load_lds(AS1(pAlo + ko), AS3(dAl), 16, 0, 0);
    #pragma unroll
    for (int cc = 0; cc < 4; cc++) {
      __builtin_amdgcn_global_load_lds(AS1(pBhi + cof + ko + cc * 8192),
                                       AS3(dBh + cc * 512), 16, 0, 0);
      __builtin_amdgcn_global_load_lds(AS1(pBlo + cof + ko + cc * 8192),
                                       AS3(dBl + cc * 512), 16, 0, 0);
    }
  };

  // ---- prologue ----
  // cq via asm loads (kept out of compiler vmcnt accounting), retired immediately
  float cq[4][4];
  {
    unsigned long long cqp = (unsigned long long)(cq_base + wc * 64 + m);
    cq[0][0] = gload_f32<0>(cqp);    cq[0][1] = gload_f32<64>(cqp);
    cq[0][2] = gload_f32<128>(cqp);  cq[0][3] = gload_f32<192>(cqp);
    cq[1][0] = gload_f32<1024>(cqp); cq[1][1] = gload_f32<1088>(cqp);
    cq[1][2] = gload_f32<1152>(cqp); cq[1][3] = gload_f32<1216>(cqp);
    cq[2][0] = gload_f32<2048>(cqp); cq[2][1] = gload_f32<2112>(cqp);
    cq[2][2] = gload_f32<2176>(cqp); cq[2][3] = gload_f32<2240>(cqp);
    cq[3][0] = gload_f32<3072>(cqp); cq[3][1] = gload_f32<3136>(cqp);
    cq[3][2] = gload_f32<3200>(cqp); cq[3][3] = gload_f32<3264>(cqp);
    asm volatile("s_waitcnt vmcnt(0)" ::: "memory");
  }

  bf16x8 f0_ah[4], f0_al[4], f0_bh[4], f0_bl[4];
  bf16x8 f1_ah[4], f1_al[4], f1_bh[4], f1_bl[4];
  f32x4 acc[4][4];

  stage(0, 0);
  asm volatile("s_waitcnt vmcnt(0)" ::: "memory");
  asm volatile("s_barrier" ::: "memory");      // buf0 readable
  __builtin_amdgcn_sched_barrier(0);

  // read frags(0) into set f0 from buf0
  f0_bh[0] = ds_read128<0>(aB);     f0_bh[1] = ds_read128<1024>(aB);
  f0_bh[2] = ds_read128<2048>(aB);  f0_bh[3] = ds_read128<3072>(aB);
  f0_bl[0] = ds_read128<16384>(aB); f0_bl[1] = ds_read128<17408>(aB);
  f0_bl[2] = ds_read128<18432>(aB); f0_bl[3] = ds_read128<19456>(aB);
  f0_ah[0] = ds_read128<0>(aA);     f0_ah[1] = ds_read128<1024>(aA);
  f0_ah[2] = ds_read128<2048>(aA);  f0_ah[3] = ds_read128<3072>(aA);
  f0_al[0] = ds_read128<4096>(aA);  f0_al[1] = ds_read128<5120>(aA);
  f0_al[2] = ds_read128<6144>(aA);  f0_al[3] = ds_read128<7168>(aA);

  stage(1, 1);
  asm volatile("s_waitcnt lgkmcnt(0)" ::: "memory");  // frags(0) in regs
  asm volatile("s_waitcnt vmcnt(0)" ::: "memory");    // tile 1 landed
  asm volatile("s_barrier" ::: "memory");             // buf1 readable
  __builtin_amdgcn_sched_barrier(0);

// BS = (T+1)&1 (buffer of read-ahead frags), SB = T&1 (stage target), as literals.
#define K_ITER(T, RD, CS, BS, SB)                                                \
  {                                                                              \
    const int t_ = (T);                                                          \
    if (t_ < 63) { /* 15 of 16 read-ahead frags(t+1) from buf BS */              \
      RD##_bh[0] = ds_read128<(BS)*32768 + 0>(aB);                               \
      RD##_bh[1] = ds_read128<(BS)*32768 + 1024>(aB);                            \
      RD##_bh[2] = ds_read128<(BS)*32768 + 2048>(aB);                            \
      RD##_bh[3] = ds_read128<(BS)*32768 + 3072>(aB);                            \
      RD##_bl[0] = ds_read128<(BS)*32768 + 16384>(aB);                           \
      RD##_bl[1] = ds_read128<(BS)*32768 + 17408>(aB);                           \
      RD##_bl[2] = ds_read128<(BS)*32768 + 18432>(aB);                           \
      RD##_bl[3] = ds_read128<(BS)*32768 + 19456>(aB);                           \
      RD##_ah[0] = ds_read128<(BS)*8192 + 0>(aA);                                \
      RD##_ah[1] = ds_read128<(BS)*8192 + 1024>(aA);                             \
      RD##_ah[2] = ds_read128<(BS)*8192 + 2048>(aA);                             \
      RD##_ah[3] = ds_read128<(BS)*8192 + 3072>(aA);                             \
      RD##_al[0] = ds_read128<(BS)*8192 + 4096>(aA);                             \
      RD##_al[1] = ds_read128<(BS)*8192 + 5120>(aA);                             \
      RD##_al[2] = ds_read128<(BS)*8192 + 6144>(aA);                             \
      /* lazy wait: retires frags(t), issued a full iteration ago */             \
      asm volatile("s_waitcnt lgkmcnt(15)" ::: "memory");                        \
    } else {                                                                     \
      asm volatile("s_waitcnt lgkmcnt(0)" ::: "memory");                         \
    }                                                                            \
    __builtin_amdgcn_sched_barrier(0);                                           \
    asm volatile("s_barrier" ::: "memory"); /* #1: all waves retired frags(t) */ \
    if (t_ < 63) RD##_al[3] = ds_read128<(BS)*8192 + 7168>(aA);                  \
    if (t_ < 62) stage(SB, t_ + 2); /* overwrite just-retired buf SB */          \
    __builtin_amdgcn_sched_barrier(0);                                           \
    if ((t_ & 15) == 0) {                                                        \
      _Pragma("unroll") for (int mi = 0; mi < 4; mi++)                           \
        _Pragma("unroll") for (int ni = 0; ni < 4; ni++)                         \
          acc[mi][ni] = (f32x4){0.f, 0.f, 0.f, 0.f};                             \
    }                                                                            \
    __builtin_amdgcn_s_setprio(1);                                               \
    _Pragma("unroll") for (int mi = 0; mi < 4; mi++)                             \
      _Pragma("unroll") for (int ni = 0; ni < 4; ni++)                           \
        acc[mi][ni] = __builtin_amdgcn_mfma_f32_16x16x32_bf16(                   \
            CS##_ah[mi], CS##_bh[ni], acc[mi][ni], 0, 0, 0);                     \
    _Pragma("unroll") for (int mi = 0; mi < 4; mi++)                             \
      _Pragma("unroll") for (int ni = 0; ni < 4; ni++)                           \
        acc[mi][ni] = __builtin_amdgcn_mfma_f32_16x16x32_bf16(                   \
            CS##_ah[mi], CS##_bl[ni], acc[mi][ni], 0, 0, 0);                     \
    _Pragma("unroll") for (int mi = 0; mi < 4; mi++)                             \
      _Pragma("unroll") for (int ni = 0; ni < 4; ni++)                           \
        acc[mi][ni] = __builtin_amdgcn_mfma_f32_16x16x32_bf16(                   \
            CS##_al[mi], CS##_bh[ni], acc[mi][ni], 0, 0, 0);                     \
    __builtin_amdgcn_s_setprio(0);                                               \
    if ((t_ & 15) == 15) { /* per-lane fold (cross-lane reduce deferred) */      \
      const int ct_ = t_ >> 4;                                                   \
      const unsigned colb = ct_ * 256 + wc * 64 + m;                             \
      _Pragma("unroll") for (int mi = 0; mi < 4; mi++)                           \
        _Pragma("unroll") for (int r = 0; r < 4; r++) {                          \
          _Pragma("unroll") for (int ni = 0; ni < 4; ni++) {                     \
            float d2 = fmaf(-2.f, acc[mi][ni][r], cq[ct_][ni]);                  \
            unsigned long long p =                                               \
                (((unsigned long long)fkey(d2)) << 32) | (colb + ni * 16);       \
            if (p < best[mi][r]) best[mi][r] = p;                                \
          }                                                                      \
        }                                                                        \
    }                                                                            \
    asm volatile("s_waitcnt vmcnt(0)" ::: "memory"); /* stage(t+2), ~2000cy old */ \
    asm volatile("s_barrier" ::: "memory");          /* #2: staging visible */   \
    __builtin_amdgcn_sched_barrier(0);                                           \
  }

  for (int tp = 0; tp < 32; tp++) {
    K_ITER(tp * 2,     f1, f0, 1, 0);   // consume set0, read set1 from buf1
    K_ITER(tp * 2 + 1, f0, f1, 0, 1);   // consume set1, read set0 from buf0
  }
#undef K_ITER

  // deferred cross-lane argmin reduce (over the 16 cols in each fragment)
  #pragma unroll
  for (int mi = 0; mi < 4; mi++)
    #pragma unroll
    for (int r = 0; r < 4; r++) {
      unsigned long long mn = best[mi][r];
      #pragma unroll
      for (int off = 1; off < 16; off <<= 1) {
        unsigned long long o = shfl_xor_u64(mn, off);
        if (o < mn) mn = o;
      }
      best[mi][r] = mn;
    }

  // overlay argmin/loss scratch into the (now dead) A region of SM
  unsigned long long* bestLDS = (unsigned long long*)&SM[0];  // [4][64]
  float* ls = (float*)(bestLDS + 256);                        // [4]
  __syncthreads();

  // publish per-row argmin quarters (wc = 0..3)
  if (m == 0) {
    #pragma unroll
    for (int mi = 0; mi < 4; mi++)
      #pragma unroll
      for (int r = 0; r < 4; r++)
        bestLDS[wc * 64 + mi * 16 + g * 4 + r] = best[mi][r];
  }
  __syncthreads();

  // ---------------- rotate epilogue: 16 rows per wave ----------------
  float lossacc = 0.f;
  for (int rr = 0; rr < 16; rr++) {
    const int row64 = w * 16 + rr;
    unsigned long long mn = bestLDS[row64];
    #pragma unroll
    for (int q2 = 1; q2 < 4; q2++) {
      unsigned long long o = bestLDS[q2 * 64 + row64];
      if (o < mn) mn = o;
    }
    const int c = (int)(mn & 0xffffffffu);
    const int row = row0 + row64;
    if (lane == 0) idx_out[(size_t)row * 8 + qi] = (float)c;

    const size_t base = (size_t)row * 512 + lane * 8;
    ushort8 h = *(const ushort8*)(Rhi + base);
    ushort8 l = *(const ushort8*)(Rlo + base);
    const float* qrow = cbq_f32 + (size_t)c * 512 + lane * 8;
    float4 q0 = *(const float4*)qrow;
    float4 q1 = *(const float4*)(qrow + 4);
    float z[8], q[8] = {q0.x, q0.y, q0.z, q0.w, q1.x, q1.y, q1.z, q1.w};
    #pragma unroll
    for (int j = 0; j < 8; j++) z[j] = bf2f(h[j]) + bf2f(l[j]);

    float zz = 0.f, qq = 0.f, zq = 0.f;
    #pragma unroll
    for (int j = 0; j < 8; j++) {
      zz = fmaf(z[j], z[j], zz);
      qq = fmaf(q[j], q[j], qq);
      zq = fmaf(z[j], q[j], zq);
    }
    #pragma unroll
    for (int off = 32; off; off >>= 1) {
      zz += __shfl_xor(zz, off);
      qq += __shfl_xor(qq, off);
      zq += __shfl_xor(zq, off);
    }

    float nz = sqrtf(zz), nq = sqrtf(qq);
    float inz = 1.f / (nz + EPS), inq = 1.f / (nq + EPS);
    float ns  = sqrtf(zz*inz*inz + 2.f*zq*inz*inq + qq*inq*inq);
    float ins = 1.f / ns;
    float zw  = (zz*inz + zq*inq) * ins;
    float zzn = zz * inz;
    float scale = nq * inz;
    float az = scale * (1.f - 2.f * zw * ins * inz);
    float aq = scale * (2.f * zzn - 2.f * zw * ins) * inq;

    if (!last) {
      #pragma unroll
      for (int j = 0; j < 8; j++) {
        float r = z[j] - (az * z[j] + aq * q[j]);
        unsigned short hh = f2bf(r);
        h[j] = hh;
        l[j] = f2bf(r - bf2f(hh));
      }
      *(ushort8*)(Rhi + base) = h;
      *(ushort8*)(Rlo + base) = l;
    } else {
      float4 x0 = *(const float4*)(x + base);
      float4 x1 = *(const float4*)(x + base + 4);
      float xv[8] = {x0.x, x0.y, x0.z, x0.w, x1.x, x1.y, x1.z, x1.w};
      float o[8];
      #pragma unroll
      for (int j = 0; j < 8; j++) {
        float r = z[j] - (az * z[j] + aq * q[j]);
        o[j] = xv[j] - r;
      }
      *(float4*)(qout + base)     = (float4){o[0], o[1], o[2], o[3]};
      *(float4*)(qout + base + 4) = (float4){o[4], o[5], o[6], o[7]};
    }
    lossacc += (zz - 2.f * zq + qq);
  }
  if (lane == 0) ls[w] = lossacc;
  __syncthreads();
  if (tid == 0)
    atomicAdd(loss_out + qi, (ls[0] + ls[1] + ls[2] + ls[3]) *
                             (1.f / (32768.f * 512.f)));
}

extern "C" void kernel_launch(void* const* d_in, const int* in_sizes, int n_in,
                              void* d_out, int out_size, void* d_ws, size_t ws_size,
                              hipStream_t stream) {
  const float* x   = (const float*)d_in[0];   // [16, 2048, 512]
  const float* cbs = (const float*)d_in[1];   // [8, 1024, 512]
  float* out = (float*)d_out;
  const size_t M = 32768, D = 512, Q = 8, C = 1024;
  float* qout     = out;                 // [M, D]
  float* idx_out  = out + M * D;         // [M, Q] (as float)
  float* loss_out = idx_out + M * Q;     // [Q]

  // ws: Rhi 32M | Rlo 32M | CBhi 8M | CBlo 8M | cbsq 32K
  unsigned short* Rhi  = (unsigned short*)d_ws;
  unsigned short* Rlo  = Rhi + M * D;
  unsigned short* CBhi = Rlo + M * D;
  unsigned short* CBlo = CBhi + Q * C * D;
  float* cbsq = (float*)(CBlo + Q * C * D);

  prep_kernel<<<512, 256, 0, stream>>>(x, cbs, Rhi, Rlo, CBhi, CBlo, cbsq, loss_out);

  for (int qi = 0; qi < (int)Q; qi++) {
    stage_kernel<<<512, 256, 0, stream>>>(
        x, cbs + (size_t)qi * C * D, Rhi, Rlo,
        CBhi + (size_t)qi * C * D, CBlo + (size_t)qi * C * D,
        cbsq + qi * C, qout, idx_out, loss_out, qi, qi == (int)Q - 1 ? 1 : 0);
  }
}

// Round 8
// 1126.936 us; speedup vs baseline: 1.3459x; 1.3459x over previous
//
#include <hip/hip_runtime.h>

#define EPS 1e-6f

typedef __attribute__((ext_vector_type(8))) short bf16x8;
typedef __attribute__((ext_vector_type(4))) float f32x4;
typedef __attribute__((ext_vector_type(8))) unsigned short ushort8;

#define AS1(p) ((const __attribute__((address_space(1))) void*)(p))
#define AS3(p) ((__attribute__((address_space(3))) void*)(p))

__device__ inline unsigned int fkey(float f) {
  unsigned int u = __float_as_uint(f);
  return (u & 0x80000000u) ? ~u : (u | 0x80000000u);
}

__device__ inline unsigned long long shfl_xor_u64(unsigned long long v, int mask) {
  unsigned int lo = (unsigned int)(v & 0xffffffffull);
  unsigned int hi = (unsigned int)(v >> 32);
  lo = (unsigned int)__shfl_xor((int)lo, mask);
  hi = (unsigned int)__shfl_xor((int)hi, mask);
  return (((unsigned long long)hi) << 32) | lo;
}

__device__ inline unsigned short f2bf(float f) {  // RNE fp32 -> bf16
  unsigned int u = __float_as_uint(f);
  u += 0x7fffu + ((u >> 16) & 1u);
  return (unsigned short)(u >> 16);
}
__device__ inline float bf2f(unsigned short h) {
  return __uint_as_float(((unsigned int)h) << 16);
}

// LDS byte-offset of a __shared__ address (AS3 pointers are 32-bit)
__device__ inline unsigned lds_off(const void* p) {
  return (unsigned)(unsigned long long)(__attribute__((address_space(3))) const void*)p;
}

// asm ds_read_b128 with immediate offset: compiler-untracked (we control lgkmcnt)
template<int OFF>
__device__ inline bf16x8 ds_read128(unsigned addr) {
  bf16x8 r;
  asm volatile("ds_read_b128 %0, %1 offset:%2" : "=v"(r) : "v"(addr), "i"(OFF));
  return r;
}

// asm global f32 load with immediate offset (keeps compiler vmcnt accounting clean)
template<int OFF>
__device__ inline float gload_f32(unsigned long long a) {
  float r;
  asm volatile("global_load_dword %0, %1, off offset:%2" : "=v"(r) : "v"(a), "i"(OFF));
  return r;
}

// ---------------- prep: splits + codebook norms + loss zero (one kernel) ----------------
__global__ __launch_bounds__(256) void prep_kernel(
    const float* __restrict__ x, const float* __restrict__ cbs,
    unsigned short* __restrict__ Rhi, unsigned short* __restrict__ Rlo,
    unsigned short* __restrict__ CBhi, unsigned short* __restrict__ CBlo,
    float* __restrict__ cbsq, float* __restrict__ loss_out) {
  constexpr size_t M = 32768, D = 512, C = 1024, Q = 8;
  const size_t nthreads = (size_t)gridDim.x * 256;
  const size_t gtid = (size_t)blockIdx.x * 256 + threadIdx.x;
  const int lane = threadIdx.x & 63;
  const int w = threadIdx.x >> 6;

  for (size_t i = gtid; i < M * D / 8; i += nthreads) {
    size_t off = i * 8;
    float4 v0 = *(const float4*)(x + off);
    float4 v1 = *(const float4*)(x + off + 4);
    float v[8] = {v0.x, v0.y, v0.z, v0.w, v1.x, v1.y, v1.z, v1.w};
    ushort8 h, l;
    #pragma unroll
    for (int j = 0; j < 8; j++) {
      unsigned short hh = f2bf(v[j]);
      h[j] = hh;
      l[j] = f2bf(v[j] - bf2f(hh));
    }
    *(ushort8*)(Rhi + off) = h;
    *(ushort8*)(Rlo + off) = l;
  }
  for (size_t i = gtid; i < Q * C * D / 8; i += nthreads) {
    size_t off = i * 8;
    float4 v0 = *(const float4*)(cbs + off);
    float4 v1 = *(const float4*)(cbs + off + 4);
    float v[8] = {v0.x, v0.y, v0.z, v0.w, v1.x, v1.y, v1.z, v1.w};
    ushort8 h, l;
    #pragma unroll
    for (int j = 0; j < 8; j++) {
      unsigned short hh = f2bf(v[j]);
      h[j] = hh;
      l[j] = f2bf(v[j] - bf2f(hh));
    }
    *(ushort8*)(CBhi + off) = h;
    *(ushort8*)(CBlo + off) = l;
  }
  for (int row = blockIdx.x * 4 + w; row < (int)(Q * C); row += gridDim.x * 4) {
    const float4* p = (const float4*)(cbs + (size_t)row * 512);
    float4 v0 = p[lane];
    float4 v1 = p[lane + 64];
    float s = v0.x*v0.x + v0.y*v0.y + v0.z*v0.z + v0.w*v0.w
            + v1.x*v1.x + v1.y*v1.y + v1.z*v1.z + v1.w*v1.w;
    #pragma unroll
    for (int off = 32; off; off >>= 1) s += __shfl_xor(s, off);
    if (lane == 0) cbsq[row] = s;
  }
  if (blockIdx.x == 0 && threadIdx.x < (int)Q) loss_out[threadIdx.x] = 0.f;
}

#define BARRIER  asm volatile("s_barrier" ::: "memory")
#define LGKM0    asm volatile("s_waitcnt lgkmcnt(0)" ::: "memory")
#define SCHEDB   __builtin_amdgcn_sched_barrier(0)

// ---------------- fused stage: 4-phase interleaved MFMA argmin + rotate ----------------
// Grid 256 x 512 threads (1 block/CU, 8 waves 2x4, wave tile 64x64, acc 4x4). Block owns
// 128 rows; 64 K-steps (4 col-tiles x 16 BK=32). 3 LDS buffers (tile t read, t+1
// resident, t+2 in flight). m201-style FINE interleave: each K-step = 4 phases, each
// {ds_read subtile | 2 stage loads | s_barrier | lgkmcnt(0) | setprio(1) | 12 MFMA
// quadrant | setprio(0) | s_barrier}. Quadrant order (A01*B01),(A01*B23),(A23*B23),
// (A23*B01) so each phase reads only its NEW frags (8/4/4/0 reads; 16/iter total, same
// as coarse) -- waves stagger across phases so the LDS pipe and MFMA pipe are fed by
// DIFFERENT waves simultaneously (the mechanism every coarse schedule R2-R7 lacked).
// Counted vmcnt(6) once per K-step at P3: forces tile t+1 (issued a full iter ago),
// leaves tile t+2's 6 loads in flight. No vmcnt(0) drain in the loop.
__global__ __launch_bounds__(512, 2) void stage_kernel(
    const float* __restrict__ x, const float* __restrict__ cbq_f32,
    unsigned short* __restrict__ Rhi, unsigned short* __restrict__ Rlo,
    const unsigned short* __restrict__ Chi, const unsigned short* __restrict__ Clo,
    const float* __restrict__ cq_base, float* __restrict__ qout,
    float* __restrict__ idx_out, float* __restrict__ loss_out,
    int qi, int last) {
  __shared__ unsigned short As[3][2][128 * 32];    // [buf][hi/lo] 48 KB
  __shared__ unsigned short Bs[3][2][256 * 32];    // [buf][hi/lo] 96 KB
  __shared__ unsigned long long bestLDS[4][128];   // 4 KB
  __shared__ float ls[8];

  const int tid = threadIdx.x;
  const int lane = tid & 63;
  const int w = tid >> 6;              // 0..7
  const int wr = w >> 2, wc = w & 3;   // wave grid 2 (rows) x 4 (cols)
  const int row0 = blockIdx.x * 128;

  // staging: lane -> (row-in-chunk rw, LDS slot oq); global octet pre-swizzled
  const int rw = lane >> 2, oq = lane & 3;
  const int o_sw = (oq - rw - (rw >> 2)) & 3;
  // fragment read: lane -> (row m, k-octet g); swizzled slot
  const int m = lane & 15, g = lane >> 4;
  const int f_sw8 = ((g + m + (m >> 2)) & 3) * 8;

  // global staging base pointers (per-lane)
  const unsigned short* pAhi = Rhi + (size_t)(row0 + w * 16 + rw) * 512 + o_sw * 8;
  const unsigned short* pAlo = Rlo + (size_t)(row0 + w * 16 + rw) * 512 + o_sw * 8;
  const unsigned short* pBhi = Chi + (size_t)(w * 32 + rw) * 512 + o_sw * 8;
  const unsigned short* pBlo = Clo + (size_t)(w * 32 + rw) * 512 + o_sw * 8;

  // LDS read base addresses (byte offsets), buf 0
  unsigned aA = lds_off(&As[0][0][(wr * 64 + m) * 32 + f_sw8]);
  unsigned aB = lds_off(&Bs[0][0][(wc * 64 + m) * 32 + f_sw8]);

  unsigned long long best[4][4];
  #pragma unroll
  for (int mi = 0; mi < 4; mi++)
    #pragma unroll
    for (int r = 0; r < 4; r++) best[mi][r] = ~0ull;

  // staging split into 3 parts of 2 global_load_lds each (spread across phases)
  auto stageA = [&](int buf, int t) {
    const size_t ko = (size_t)((t & 15) * 32);
    __builtin_amdgcn_global_load_lds(AS1(pAhi + ko), AS3(&As[buf][0][w * 512]), 16, 0, 0);
    __builtin_amdgcn_global_load_lds(AS1(pAlo + ko), AS3(&As[buf][1][w * 512]), 16, 0, 0);
  };
  auto stageB1 = [&](int buf, int t) {
    const size_t ko = (size_t)((t & 15) * 32);
    const size_t cof = (size_t)((t >> 4) * 256) * 512;
    unsigned short* dBh = &Bs[buf][0][w * 1024];
    __builtin_amdgcn_global_load_lds(AS1(pBhi + cof + ko), AS3(dBh), 16, 0, 0);
    __builtin_amdgcn_global_load_lds(AS1(pBhi + cof + ko + 8192), AS3(dBh + 512), 16, 0, 0);
  };
  auto stageB2 = [&](int buf, int t) {
    const size_t ko = (size_t)((t & 15) * 32);
    const size_t cof = (size_t)((t >> 4) * 256) * 512;
    unsigned short* dBl = &Bs[buf][1][w * 1024];
    __builtin_amdgcn_global_load_lds(AS1(pBlo + cof + ko), AS3(dBl), 16, 0, 0);
    __builtin_amdgcn_global_load_lds(AS1(pBlo + cof + ko + 8192), AS3(dBl + 512), 16, 0, 0);
  };

  // ---- prologue ----
  // cq via asm loads (kept out of compiler vmcnt accounting), retired immediately
  float cq[4][4];
  {
    unsigned long long cqp = (unsigned long long)(cq_base + wc * 64 + m);
    cq[0][0] = gload_f32<0>(cqp);    cq[0][1] = gload_f32<64>(cqp);
    cq[0][2] = gload_f32<128>(cqp);  cq[0][3] = gload_f32<192>(cqp);
    cq[1][0] = gload_f32<1024>(cqp); cq[1][1] = gload_f32<1088>(cqp);
    cq[1][2] = gload_f32<1152>(cqp); cq[1][3] = gload_f32<1216>(cqp);
    cq[2][0] = gload_f32<2048>(cqp); cq[2][1] = gload_f32<2112>(cqp);
    cq[2][2] = gload_f32<2176>(cqp); cq[2][3] = gload_f32<2240>(cqp);
    cq[3][0] = gload_f32<3072>(cqp); cq[3][1] = gload_f32<3136>(cqp);
    cq[3][2] = gload_f32<3200>(cqp); cq[3][3] = gload_f32<3264>(cqp);
    asm volatile("s_waitcnt vmcnt(0)" ::: "memory");
  }

  // fill buffers 0,1 with tiles 0,1
  stageA(0, 0); stageB1(0, 0); stageB2(0, 0);
  stageA(1, 1); stageB1(1, 1); stageB2(1, 1);
  asm volatile("s_waitcnt vmcnt(6)" ::: "memory");  // tile 0 landed; tile 1 in flight
  BARRIER;
  SCHEDB;

  bf16x8 ah[4], al[4], bh[4], bl[4];
  f32x4 acc[4][4];
  int bn = 0;   // buf holding tile t (reads)
  int bst = 2;  // buf target for stage(t+2)

  for (int t = 0; t < 64; ++t) {
    const int kk = t & 15;

    // ================= P0: read A01+B01, stage A(t+2), MFMA Q0 = A01*B01 ========
    ah[0] = ds_read128<0>(aA);     ah[1] = ds_read128<1024>(aA);
    al[0] = ds_read128<8192>(aA);  al[1] = ds_read128<9216>(aA);
    bh[0] = ds_read128<0>(aB);     bh[1] = ds_read128<1024>(aB);
    bl[0] = ds_read128<16384>(aB); bl[1] = ds_read128<17408>(aB);
    if (t < 62) stageA(bst, t + 2);
    if (kk == 0) {
      #pragma unroll
      for (int mi = 0; mi < 4; mi++)
        #pragma unroll
        for (int ni = 0; ni < 4; ni++)
          acc[mi][ni] = (f32x4){0.f, 0.f, 0.f, 0.f};
    }
    BARRIER; LGKM0; SCHEDB;
    __builtin_amdgcn_s_setprio(1);
    #pragma unroll
    for (int mi = 0; mi < 2; mi++)
      #pragma unroll
      for (int ni = 0; ni < 2; ni++)
        acc[mi][ni] = __builtin_amdgcn_mfma_f32_16x16x32_bf16(ah[mi], bh[ni], acc[mi][ni], 0, 0, 0);
    #pragma unroll
    for (int mi = 0; mi < 2; mi++)
      #pragma unroll
      for (int ni = 0; ni < 2; ni++)
        acc[mi][ni] = __builtin_amdgcn_mfma_f32_16x16x32_bf16(ah[mi], bl[ni], acc[mi][ni], 0, 0, 0);
    #pragma unroll
    for (int mi = 0; mi < 2; mi++)
      #pragma unroll
      for (int ni = 0; ni < 2; ni++)
        acc[mi][ni] = __builtin_amdgcn_mfma_f32_16x16x32_bf16(al[mi], bh[ni], acc[mi][ni], 0, 0, 0);
    __builtin_amdgcn_s_setprio(0);
    BARRIER; SCHEDB;

    // ================= P1: read B23, stage Bhi(t+2), MFMA Q1 = A01*B23 ==========
    bh[2] = ds_read128<2048>(aB);  bh[3] = ds_read128<3072>(aB);
    bl[2] = ds_read128<18432>(aB); bl[3] = ds_read128<19456>(aB);
    if (t < 62) stageB1(bst, t + 2);
    BARRIER; LGKM0; SCHEDB;
    __builtin_amdgcn_s_setprio(1);
    #pragma unroll
    for (int mi = 0; mi < 2; mi++)
      #pragma unroll
      for (int ni = 2; ni < 4; ni++)
        acc[mi][ni] = __builtin_amdgcn_mfma_f32_16x16x32_bf16(ah[mi], bh[ni], acc[mi][ni], 0, 0, 0);
    #pragma unroll
    for (int mi = 0; mi < 2; mi++)
      #pragma unroll
      for (int ni = 2; ni < 4; ni++)
        acc[mi][ni] = __builtin_amdgcn_mfma_f32_16x16x32_bf16(ah[mi], bl[ni], acc[mi][ni], 0, 0, 0);
    #pragma unroll
    for (int mi = 0; mi < 2; mi++)
      #pragma unroll
      for (int ni = 2; ni < 4; ni++)
        acc[mi][ni] = __builtin_amdgcn_mfma_f32_16x16x32_bf16(al[mi], bh[ni], acc[mi][ni], 0, 0, 0);
    __builtin_amdgcn_s_setprio(0);
    BARRIER; SCHEDB;

    // ================= P2: read A23, stage Blo(t+2), MFMA Q2 = A23*B23 ==========
    ah[2] = ds_read128<2048>(aA);  ah[3] = ds_read128<3072>(aA);
    al[2] = ds_read128<10240>(aA); al[3] = ds_read128<11264>(aA);
    if (t < 62) stageB2(bst, t + 2);
    BARRIER; LGKM0; SCHEDB;
    __builtin_amdgcn_s_setprio(1);
    #pragma unroll
    for (int mi = 2; mi < 4; mi++)
      #pragma unroll
      for (int ni = 2; ni < 4; ni++)
        acc[mi][ni] = __builtin_amdgcn_mfma_f32_16x16x32_bf16(ah[mi], bh[ni], acc[mi][ni], 0, 0, 0);
    #pragma unroll
    for (int mi = 2; mi < 4; mi++)
      #pragma unroll
      for (int ni = 2; ni < 4; ni++)
        acc[mi][ni] = __builtin_amdgcn_mfma_f32_16x16x32_bf16(ah[mi], bl[ni], acc[mi][ni], 0, 0, 0);
    #pragma unroll
    for (int mi = 2; mi < 4; mi++)
      #pragma unroll
      for (int ni = 2; ni < 4; ni++)
        acc[mi][ni] = __builtin_amdgcn_mfma_f32_16x16x32_bf16(al[mi], bh[ni], acc[mi][ni], 0, 0, 0);
    __builtin_amdgcn_s_setprio(0);
    BARRIER; SCHEDB;

    // ================= P3: MFMA Q3 = A23*B01, fold, counted vmcnt ===============
    __builtin_amdgcn_s_setprio(1);
    #pragma unroll
    for (int mi = 2; mi < 4; mi++)
      #pragma unroll
      for (int ni = 0; ni < 2; ni++)
        acc[mi][ni] = __builtin_amdgcn_mfma_f32_16x16x32_bf16(ah[mi], bh[ni], acc[mi][ni], 0, 0, 0);
    #pragma unroll
    for (int mi = 2; mi < 4; mi++)
      #pragma unroll
      for (int ni = 0; ni < 2; ni++)
        acc[mi][ni] = __builtin_amdgcn_mfma_f32_16x16x32_bf16(ah[mi], bl[ni], acc[mi][ni], 0, 0, 0);
    #pragma unroll
    for (int mi = 2; mi < 4; mi++)
      #pragma unroll
      for (int ni = 0; ni < 2; ni++)
        acc[mi][ni] = __builtin_amdgcn_mfma_f32_16x16x32_bf16(al[mi], bh[ni], acc[mi][ni], 0, 0, 0);
    __builtin_amdgcn_s_setprio(0);
    if (kk == 15) { // per-lane fold (cross-lane reduce deferred to after loop)
      const int ct_ = t >> 4;
      const unsigned colb = ct_ * 256 + wc * 64 + m;
      #pragma unroll
      for (int mi = 0; mi < 4; mi++)
        #pragma unroll
        for (int r = 0; r < 4; r++) {
          #pragma unroll
          for (int ni = 0; ni < 4; ni++) {
            float d2 = fmaf(-2.f, acc[mi][ni][r], cq[ct_][ni]);
            unsigned long long p =
                (((unsigned long long)fkey(d2)) << 32) | (colb + ni * 16);
            if (p < best[mi][r]) best[mi][r] = p;
          }
        }
    }
    // counted wait: tile t+1 (issued a full iter ago) forced; t+2 stays in flight
    if (t < 62) asm volatile("s_waitcnt vmcnt(6)" ::: "memory");
    else        asm volatile("s_waitcnt vmcnt(0)" ::: "memory");
    BARRIER; SCHEDB;

    // advance read buffer to tile t+1; advance stage target
    const int s_ = (bn == 2) ? -2 : 1;
    aA += s_ * 16384; aB += s_ * 32768;
    bn = (bn == 2) ? 0 : bn + 1;
    bst = (bst == 2) ? 0 : bst + 1;
  }

  // deferred cross-lane argmin reduce (over the 16 cols in each fragment)
  #pragma unroll
  for (int mi = 0; mi < 4; mi++)
    #pragma unroll
    for (int r = 0; r < 4; r++) {
      unsigned long long mn = best[mi][r];
      #pragma unroll
      for (int off = 1; off < 16; off <<= 1) {
        unsigned long long o = shfl_xor_u64(mn, off);
        if (o < mn) mn = o;
      }
      best[mi][r] = mn;
    }

  // publish per-row argmin quarters (wc = 0..3) to LDS
  if (m == 0) {
    #pragma unroll
    for (int mi = 0; mi < 4; mi++)
      #pragma unroll
      for (int r = 0; r < 4; r++)
        bestLDS[wc][wr * 64 + mi * 16 + g * 4 + r] = best[mi][r];
  }
  __syncthreads();

  // ---------------- rotate epilogue: 16 rows per wave ----------------
  float lossacc = 0.f;
  for (int rr = 0; rr < 16; rr++) {
    const int row128 = w * 16 + rr;
    unsigned long long mn = bestLDS[0][row128];
    #pragma unroll
    for (int q2 = 1; q2 < 4; q2++) {
      unsigned long long o = bestLDS[q2][row128];
      if (o < mn) mn = o;
    }
    const int c = (int)(mn & 0xffffffffu);
    const int row = row0 + row128;
    if (lane == 0) idx_out[(size_t)row * 8 + qi] = (float)c;

    const size_t base = (size_t)row * 512 + lane * 8;
    ushort8 h = *(const ushort8*)(Rhi + base);
    ushort8 l = *(const ushort8*)(Rlo + base);
    const float* qrow = cbq_f32 + (size_t)c * 512 + lane * 8;
    float4 q0 = *(const float4*)qrow;
    float4 q1 = *(const float4*)(qrow + 4);
    float z[8], q[8] = {q0.x, q0.y, q0.z, q0.w, q1.x, q1.y, q1.z, q1.w};
    #pragma unroll
    for (int j = 0; j < 8; j++) z[j] = bf2f(h[j]) + bf2f(l[j]);

    float zz = 0.f, qq = 0.f, zq = 0.f;
    #pragma unroll
    for (int j = 0; j < 8; j++) {
      zz = fmaf(z[j], z[j], zz);
      qq = fmaf(q[j], q[j], qq);
      zq = fmaf(z[j], q[j], zq);
    }
    #pragma unroll
    for (int off = 32; off; off >>= 1) {
      zz += __shfl_xor(zz, off);
      qq += __shfl_xor(qq, off);
      zq += __shfl_xor(zq, off);
    }

    float nz = sqrtf(zz), nq = sqrtf(qq);
    float inz = 1.f / (nz + EPS), inq = 1.f / (nq + EPS);
    float ns  = sqrtf(zz*inz*inz + 2.f*zq*inz*inq + qq*inq*inq);
    float ins = 1.f / ns;
    float zw  = (zz*inz + zq*inq) * ins;
    float zzn = zz * inz;
    float scale = nq * inz;
    float az = scale * (1.f - 2.f * zw * ins * inz);
    float aq = scale * (2.f * zzn - 2.f * zw * ins) * inq;

    if (!last) {
      #pragma unroll
      for (int j = 0; j < 8; j++) {
        float r = z[j] - (az * z[j] + aq * q[j]);
        unsigned short hh = f2bf(r);
        h[j] = hh;
        l[j] = f2bf(r - bf2f(hh));
      }
      *(ushort8*)(Rhi + base) = h;
      *(ushort8*)(Rlo + base) = l;
    } else {
      float4 x0 = *(const float4*)(x + base);
      float4 x1 = *(const float4*)(x + base + 4);
      float xv[8] = {x0.x, x0.y, x0.z, x0.w, x1.x, x1.y, x1.z, x1.w};
      float o[8];
      #pragma unroll
      for (int j = 0; j < 8; j++) {
        float r = z[j] - (az * z[j] + aq * q[j]);
        o[j] = xv[j] - r;
      }
      *(float4*)(qout + base)     = (float4){o[0], o[1], o[2], o[3]};
      *(float4*)(qout + base + 4) = (float4){o[4], o[5], o[6], o[7]};
    }
    lossacc += (zz - 2.f * zq + qq);
  }
  if (lane == 0) ls[w] = lossacc;
  __syncthreads();
  if (tid == 0)
    atomicAdd(loss_out + qi, (ls[0] + ls[1] + ls[2] + ls[3] +
                              ls[4] + ls[5] + ls[6] + ls[7]) *
                             (1.f / (32768.f * 512.f)));
}

extern "C" void kernel_launch(void* const* d_in, const int* in_sizes, int n_in,
                              void* d_out, int out_size, void* d_ws, size_t ws_size,
                              hipStream_t stream) {
  const float* x   = (const float*)d_in[0];   // [16, 2048, 512]
  const float* cbs = (const float*)d_in[1];   // [8, 1024, 512]
  float* out = (float*)d_out;
  const size_t M = 32768, D = 512, Q = 8, C = 1024;
  float* qout     = out;                 // [M, D]
  float* idx_out  = out + M * D;         // [M, Q] (as float)
  float* loss_out = idx_out + M * Q;     // [Q]

  // ws: Rhi 32M | Rlo 32M | CBhi 8M | CBlo 8M | cbsq 32K
  unsigned short* Rhi  = (unsigned short*)d_ws;
  unsigned short* Rlo  = Rhi + M * D;
  unsigned short* CBhi = Rlo + M * D;
  unsigned short* CBlo = CBhi + Q * C * D;
  float* cbsq = (float*)(CBlo + Q * C * D);

  prep_kernel<<<512, 256, 0, stream>>>(x, cbs, Rhi, Rlo, CBhi, CBlo, cbsq, loss_out);

  for (int qi = 0; qi < (int)Q; qi++) {
    stage_kernel<<<256, 512, 0, stream>>>(
        x, cbs + (size_t)qi * C * D, Rhi, Rlo,
        CBhi + (size_t)qi * C * D, CBlo + (size_t)qi * C * D,
        cbsq + qi * C, qout, idx_out, loss_out, qi, qi == (int)Q - 1 ? 1 : 0);
  }
}